// Round 10
// baseline (79.990 us; speedup 1.0000x reference)
//
#include <hip/hip_runtime.h>

#define DIM   4096
#define BATCH 2048
#define KNZ   40
#define ROWS  8
#define TPB   512
#define DPT   (DIM / TPB)   // 8 d's per thread

#if __has_builtin(__builtin_amdgcn_cvt_pk_fp8_f32) && __has_builtin(__builtin_amdgcn_cvt_pk_f32_fp8)
#define HAVE_FP8 1
#else
#define HAVE_FP8 0
#endif

typedef int   i32x2 __attribute__((ext_vector_type(2)));
typedef float f32x2 __attribute__((ext_vector_type(2)));

// |wave|max measured ~6e4 (R0 zero-output absmax). 1/256 -> max ~234 < 448.
// Clamp to +-440 pre-encode makes overflow->NaN impossible for ANY data.
#define F8_SCALE   0.00390625f   // 1/256
#define F8_INV     256.0f
#define F8_CLAMP   440.0f

__device__ __forceinline__ float shflx(float v, int m) { return __shfl_xor(v, m, 64); }
__device__ __forceinline__ float shfls(float v, int s) { return __shfl(v, s, 64); }

// bf16 image: byte offset of the 16B row-group (8 bf16 rows) for dim d. R4-proven.
__device__ __forceinline__ int swz8(int d) { return (d << 4) ^ ((d >> 2) & 0x1f0); }
// fp8 image: byte offset of the 8B row-group (8 fp8 rows) for dim d.
__device__ __forceinline__ int swzf(int d) { return (d << 3) ^ (((d >> 6) & 31) << 3); }

__device__ __forceinline__ unsigned short bfp(float f) {   // f32 -> bf16 RNE
  unsigned u = __float_as_uint(f);
  u += 0x7fffu + ((u >> 16) & 1u);
  return (unsigned short)(u >> 16);
}
__device__ __forceinline__ float bfu(unsigned short h) { return __uint_as_float(((unsigned)h) << 16); }
__device__ __forceinline__ float blo(unsigned u) { return __uint_as_float(u << 16); }
__device__ __forceinline__ float bhic(unsigned u) { return __uint_as_float(u & 0xffff0000u); }

#if HAVE_FP8
__device__ __forceinline__ unsigned char f8enc(float f) {
  float c = fminf(fmaxf(f, -F8_CLAMP), F8_CLAMP);   // no overflow -> no NaN
  return (unsigned char)(__builtin_amdgcn_cvt_pk_fp8_f32(c, c, 0, false) & 0xFF);
}
#endif

template<int CTRL>
__device__ __forceinline__ float dppf(float x) {
  int i = __float_as_int(x);
  return __int_as_float(__builtin_amdgcn_update_dpp(i, i, CTRL, 0xF, 0xF, false));
}

// In-lane stage for h <= 32: blocks of 2H inside each lane's 64-elem chunk.
template<int H>
__device__ __forceinline__ void stage_inlane(float v[64]) {
#pragma unroll
  for (int o = 0; o < 64; o += 2 * H) {
    float dt[H];
#pragma unroll
    for (int i = 0; i < H; ++i) {
      float a = v[o + i], b = v[o + H + i];
      dt[i] = a - b;
      v[o + i] = a + b;
    }
#pragma unroll
    for (int i = H - 1; i >= 1; --i) v[o + H + i] = dt[i] + dt[i - 1];
    v[o + H] = dt[0] + dt[H - 1];
  }
}

// Cross-lane stage for h >= 64 (HL = h/64). Select-free fma form (R8-proven).
template<int HL>
__device__ __forceinline__ void stage_xlane(float v[64], int lane) {
  const bool up = (lane & HL) != 0;
  const float sgn   = up ? -1.0f : 1.0f;
  const float cswap = up ? -2.0f : 0.0f;
  const float rm    = up ? 1.0f : 0.0f;
  const int srcl = ((lane & (HL - 1)) == 0) ? (lane | (HL - 1)) : (lane - 1);
#pragma unroll
  for (int r = 0; r < 64; ++r) {
    float self = v[r];
    bool done = false;
#if __has_builtin(__builtin_amdgcn_permlane32_swap)
    if constexpr (HL == 32) {
      i32x2 rr = __builtin_amdgcn_permlane32_swap(__float_as_int(self), __float_as_int(self), false, false);
      float s2 = __int_as_float(rr.x) + __int_as_float(rr.y);
      v[r] = fmaf(self, cswap, s2);
      done = true;
    }
#endif
#if __has_builtin(__builtin_amdgcn_permlane16_swap)
    if constexpr (HL == 16) {
      i32x2 rr = __builtin_amdgcn_permlane16_swap(__float_as_int(self), __float_as_int(self), false, false);
      float s2 = __int_as_float(rr.x) + __int_as_float(rr.y);
      v[r] = fmaf(self, cswap, s2);
      done = true;
    }
#endif
    if (!done) {
      float pv;
      if constexpr (HL == 8)      pv = dppf<0x128>(self);
      else if constexpr (HL == 2) pv = dppf<0x4E>(self);
      else if constexpr (HL == 1) pv = dppf<0xB1>(self);
      else                        pv = shflx(self, HL);
      v[r] = fmaf(self, sgn, pv);
    }
  }
  float dw = shfls(v[63], srcl);
#pragma unroll
  for (int r = 63; r >= 1; --r) v[r] = fmaf(v[r - 1], rm, v[r]);
  v[0] = fmaf(dw, rm, v[0]);
}

__device__ __forceinline__ void fhh_regs(float v[64], int lane) {
  stage_xlane<32>(v, lane);
  stage_xlane<16>(v, lane);
  stage_xlane<8>(v, lane);
  stage_xlane<4>(v, lane);
  stage_xlane<2>(v, lane);
  stage_xlane<1>(v, lane);
  stage_inlane<32>(v);
  stage_inlane<16>(v);
  stage_inlane<8>(v);
  stage_inlane<4>(v);
  stage_inlane<2>(v);
  stage_inlane<1>(v);
}

// Prep: pre-swizzle engram indices to fp8-image byte offsets.
__global__ void prep_idx(const int* __restrict__ I, int* __restrict__ PS, int n) {
  int i = blockIdx.x * 256 + threadIdx.x;
  if (i < n) PS[i] = swzf(I[i]);
}

template<bool PRE>
__global__ __launch_bounds__(TPB, 2) void aleph_fused(
    const float* __restrict__ x, const float* __restrict__ sw,
    const float* __restrict__ V, const int* __restrict__ IDX,
    float* __restrict__ out) {
  __shared__ unsigned short img[DIM * ROWS];      // 64 KB bf16 (self + reload)
#if HAVE_FP8
  __shared__ unsigned char f8img[DIM * ROWS];     // 32 KB fp8 (sparse probes)
  char* fb = (char*)f8img;
#endif
  char* lb = (char*)img;
  const int t = threadIdx.x;
  const int w = t >> 6;          // wave id = row within block (0..7)
  const int lane = t & 63;
  const size_t row = (size_t)blockIdx.x * ROWS + w;

  float v[64];
  {
    const float4* xp = (const float4*)(x + row * DIM + (size_t)lane * 64);
#pragma unroll
    for (int i = 0; i < 16; ++i) {
      float4 f = xp[i];
      v[4 * i] = f.x; v[4 * i + 1] = f.y; v[4 * i + 2] = f.z; v[4 * i + 3] = f.w;
    }
  }
  fhh_regs(v, lane);   // wave chunk: lane holds d = 64*lane + r

#pragma unroll
  for (int r = 0; r < 64; ++r) {
    const int d = 64 * lane + r;
    *(unsigned short*)(lb + swz8(d) + 2 * w) = bfp(v[r]);
#if HAVE_FP8
    fb[swzf(d) + w] = f8enc(v[r] * F8_SCALE);
#endif
  }
  __syncthreads();

  // Gather: thread t owns d = ii*512 + t.
  // Self term from bf16 image (b128); 40 sparse probes from fp8 image (b64).
  float preg[DPT][ROWS];
#pragma unroll
  for (int ii = 0; ii < DPT; ++ii) {
    const int d = ii * TPB + t;
    const float swd = sw[d];
    uint4 q = *(const uint4*)(lb + swz8(d));
    float a0 = blo(q.x) * swd, a1 = bhic(q.x) * swd;
    float a2 = blo(q.y) * swd, a3 = bhic(q.y) * swd;
    float a4 = blo(q.z) * swd, a5 = bhic(q.z) * swd;
    float a6 = blo(q.w) * swd, a7 = bhic(q.w) * swd;
    const int4*   ip = (const int4*)(IDX + d * KNZ);   // PRE: swzf offsets; else raw idx
    const float4* vp = (const float4*)(V + d * KNZ);
#if HAVE_FP8
    float s0 = 0.f, s1 = 0.f, s2 = 0.f, s3 = 0.f, s4 = 0.f, s5 = 0.f, s6 = 0.f, s7 = 0.f;
#pragma unroll 5
    for (int g = 0; g < KNZ / 4; ++g) {
      int4 i4 = ip[g];
      float4 f4 = vp[g];
      int o0, o1, o2, o3;
      if constexpr (PRE) { o0 = i4.x; o1 = i4.y; o2 = i4.z; o3 = i4.w; }
      else { o0 = swzf(i4.x); o1 = swzf(i4.y); o2 = swzf(i4.z); o3 = swzf(i4.w); }
      {
        uint2 qa = *(const uint2*)(fb + o0);
        f32x2 p01 = __builtin_amdgcn_cvt_pk_f32_fp8(qa.x, false);
        f32x2 p23 = __builtin_amdgcn_cvt_pk_f32_fp8(qa.x, true);
        f32x2 p45 = __builtin_amdgcn_cvt_pk_f32_fp8(qa.y, false);
        f32x2 p67 = __builtin_amdgcn_cvt_pk_f32_fp8(qa.y, true);
        s0 += p01.x * f4.x; s1 += p01.y * f4.x; s2 += p23.x * f4.x; s3 += p23.y * f4.x;
        s4 += p45.x * f4.x; s5 += p45.y * f4.x; s6 += p67.x * f4.x; s7 += p67.y * f4.x;
      }
      {
        uint2 qa = *(const uint2*)(fb + o1);
        f32x2 p01 = __builtin_amdgcn_cvt_pk_f32_fp8(qa.x, false);
        f32x2 p23 = __builtin_amdgcn_cvt_pk_f32_fp8(qa.x, true);
        f32x2 p45 = __builtin_amdgcn_cvt_pk_f32_fp8(qa.y, false);
        f32x2 p67 = __builtin_amdgcn_cvt_pk_f32_fp8(qa.y, true);
        s0 += p01.x * f4.y; s1 += p01.y * f4.y; s2 += p23.x * f4.y; s3 += p23.y * f4.y;
        s4 += p45.x * f4.y; s5 += p45.y * f4.y; s6 += p67.x * f4.y; s7 += p67.y * f4.y;
      }
      {
        uint2 qa = *(const uint2*)(fb + o2);
        f32x2 p01 = __builtin_amdgcn_cvt_pk_f32_fp8(qa.x, false);
        f32x2 p23 = __builtin_amdgcn_cvt_pk_f32_fp8(qa.x, true);
        f32x2 p45 = __builtin_amdgcn_cvt_pk_f32_fp8(qa.y, false);
        f32x2 p67 = __builtin_amdgcn_cvt_pk_f32_fp8(qa.y, true);
        s0 += p01.x * f4.z; s1 += p01.y * f4.z; s2 += p23.x * f4.z; s3 += p23.y * f4.z;
        s4 += p45.x * f4.z; s5 += p45.y * f4.z; s6 += p67.x * f4.z; s7 += p67.y * f4.z;
      }
      {
        uint2 qa = *(const uint2*)(fb + o3);
        f32x2 p01 = __builtin_amdgcn_cvt_pk_f32_fp8(qa.x, false);
        f32x2 p23 = __builtin_amdgcn_cvt_pk_f32_fp8(qa.x, true);
        f32x2 p45 = __builtin_amdgcn_cvt_pk_f32_fp8(qa.y, false);
        f32x2 p67 = __builtin_amdgcn_cvt_pk_f32_fp8(qa.y, true);
        s0 += p01.x * f4.w; s1 += p01.y * f4.w; s2 += p23.x * f4.w; s3 += p23.y * f4.w;
        s4 += p45.x * f4.w; s5 += p45.y * f4.w; s6 += p67.x * f4.w; s7 += p67.y * f4.w;
      }
    }
    preg[ii][0] = fmaf(s0, F8_INV, a0); preg[ii][1] = fmaf(s1, F8_INV, a1);
    preg[ii][2] = fmaf(s2, F8_INV, a2); preg[ii][3] = fmaf(s3, F8_INV, a3);
    preg[ii][4] = fmaf(s4, F8_INV, a4); preg[ii][5] = fmaf(s5, F8_INV, a5);
    preg[ii][6] = fmaf(s6, F8_INV, a6); preg[ii][7] = fmaf(s7, F8_INV, a7);
#else
    // Fallback: R8-proven bf16 b128 probes.
#pragma unroll 5
    for (int g = 0; g < KNZ / 4; ++g) {
      int4 i4 = ip[g];
      float4 f4 = vp[g];
      int o0 = swz8(i4.x), o1 = swz8(i4.y), o2 = swz8(i4.z), o3 = swz8(i4.w);
      {
        uint4 qa = *(const uint4*)(lb + o0);
        a0 += blo(qa.x) * f4.x; a1 += bhic(qa.x) * f4.x;
        a2 += blo(qa.y) * f4.x; a3 += bhic(qa.y) * f4.x;
        a4 += blo(qa.z) * f4.x; a5 += bhic(qa.z) * f4.x;
        a6 += blo(qa.w) * f4.x; a7 += bhic(qa.w) * f4.x;
      }
      {
        uint4 qa = *(const uint4*)(lb + o1);
        a0 += blo(qa.x) * f4.y; a1 += bhic(qa.x) * f4.y;
        a2 += blo(qa.y) * f4.y; a3 += bhic(qa.y) * f4.y;
        a4 += blo(qa.z) * f4.y; a5 += bhic(qa.z) * f4.y;
        a6 += blo(qa.w) * f4.y; a7 += bhic(qa.w) * f4.y;
      }
      {
        uint4 qa = *(const uint4*)(lb + o2);
        a0 += blo(qa.x) * f4.z; a1 += bhic(qa.x) * f4.z;
        a2 += blo(qa.y) * f4.z; a3 += bhic(qa.y) * f4.z;
        a4 += blo(qa.z) * f4.z; a5 += bhic(qa.z) * f4.z;
        a6 += blo(qa.w) * f4.z; a7 += bhic(qa.w) * f4.z;
      }
      {
        uint4 qa = *(const uint4*)(lb + o3);
        a0 += blo(qa.x) * f4.w; a1 += bhic(qa.x) * f4.w;
        a2 += blo(qa.y) * f4.w; a3 += bhic(qa.y) * f4.w;
        a4 += blo(qa.z) * f4.w; a5 += bhic(qa.z) * f4.w;
        a6 += blo(qa.w) * f4.w; a7 += bhic(qa.w) * f4.w;
      }
    }
    preg[ii][0] = a0; preg[ii][1] = a1; preg[ii][2] = a2; preg[ii][3] = a3;
    preg[ii][4] = a4; preg[ii][5] = a5; preg[ii][6] = a6; preg[ii][7] = a7;
#endif
  }
  __syncthreads();   // all gathers done before in-place overwrite

#pragma unroll
  for (int ii = 0; ii < DPT; ++ii) {
    const int d = ii * TPB + t;
    uint4 pk;
    pk.x = (unsigned)bfp(preg[ii][0]) | ((unsigned)bfp(preg[ii][1]) << 16);
    pk.y = (unsigned)bfp(preg[ii][2]) | ((unsigned)bfp(preg[ii][3]) << 16);
    pk.z = (unsigned)bfp(preg[ii][4]) | ((unsigned)bfp(preg[ii][5]) << 16);
    pk.w = (unsigned)bfp(preg[ii][6]) | ((unsigned)bfp(preg[ii][7]) << 16);
    *(uint4*)(lb + swz8(d)) = pk;
  }
  __syncthreads();

#pragma unroll
  for (int r = 0; r < 64; ++r)
    v[r] = bfu(*(const unsigned short*)(lb + swz8(64 * lane + r) + 2 * w));
  fhh_regs(v, lane);

  const float inv = 1.0f / (float)DIM;
  float4* op = (float4*)(out + row * DIM + (size_t)lane * 64);
#pragma unroll
  for (int i = 0; i < 16; ++i) {
    float4 f;
    f.x = v[4 * i] * inv;     f.y = v[4 * i + 1] * inv;
    f.z = v[4 * i + 2] * inv; f.w = v[4 * i + 3] * inv;
    op[i] = f;
  }
}

extern "C" void kernel_launch(void* const* d_in, const int* in_sizes, int n_in,
                              void* d_out, int out_size, void* d_ws, size_t ws_size,
                              hipStream_t stream) {
  const float* x  = (const float*)d_in[0];   // (2048, 4096) f32
  const float* sw = (const float*)d_in[1];   // (4096,) f32
  const float* V  = (const float*)d_in[2];   // (4096, 40) f32
  const int*   I  = (const int*)d_in[3];     // (4096, 40) i32
  float* out = (float*)d_out;                // (2048, 4096) f32

  dim3 grid(BATCH / ROWS), block(TPB);
  const int nidx = DIM * KNZ;                // 163840
#if HAVE_FP8
  if (ws_size >= (size_t)nidx * sizeof(int)) {
    int* PS = (int*)d_ws;
    hipLaunchKernelGGL(prep_idx, dim3((nidx + 255) / 256), dim3(256), 0, stream, I, PS, nidx);
    hipLaunchKernelGGL(aleph_fused<true>, grid, block, 0, stream, x, sw, V, PS, out);
    return;
  }
#endif
  hipLaunchKernelGGL(aleph_fused<false>, grid, block, 0, stream, x, sw, V, I, out);
}